// Round 1
// baseline (744.465 us; speedup 1.0000x reference)
//
#include <hip/hip_runtime.h>

// out[b,n] = sum_{c,hw} x[b,c,hw] * W_s[n,hw] * W_d[n,c] + W_b[n]
// B=512, C=384, N=512, HW=169 (13x13).
//
// Plan: per block = (one b, one 128-wide c-tile, one 128-wide n-tile):
//   stage bf16 tiles of x[b, c-tile, :] (A: [c][k]) and W_s[n-tile, :] (B: [n][k])
//   in LDS (K=169 padded to 192, staged in two 96-chunks, 53 KB total),
//   MFMA 16x16x32_bf16 into 128x128 fp32 accumulators (4 waves, 64x64 each),
//   epilogue: weight by W_d[n,c], reduce over c (regs + shfl_xor 16/32),
//   atomicAdd into zeroed d_out; bias added once by the c_blk==0/cq==0 wave.

#define B_   512
#define C_   384
#define N_   512
#define HW_  169
#define KCH  96        // K elements staged per chunk (3 MFMA k-steps)
#define LDSS 104       // LDS row stride in bf16 (208 B = 52 dw; 52%32=20 -> 2-way, free)
#define CT   128
#define NT   128

typedef __bf16 bf16x8 __attribute__((ext_vector_type(8)));
typedef float f32x4  __attribute__((ext_vector_type(4)));

__device__ __forceinline__ __bf16 f2bf(float f) {
  union { float f; unsigned u; } v; v.f = f;
  unsigned r = (v.u + 0x7FFFu + ((v.u >> 16) & 1u)) >> 16;   // RNE truncate
  unsigned short s = (unsigned short)r;
  return __builtin_bit_cast(__bf16, s);
}

__global__ void transpose_wd_kernel(const float* __restrict__ Wd,
                                    float* __restrict__ WdT) {
  int idx = blockIdx.x * 256 + threadIdx.x;   // over C_*N_ = 196608, [c][n] order
  if (idx < C_ * N_) {
    int c = idx >> 9;          // / 512
    int n = idx & (N_ - 1);    // % 512
    WdT[idx] = Wd[n * C_ + c];
  }
}

__global__ __launch_bounds__(256)
void conv_encoder_main(const float* __restrict__ x,
                       const float* __restrict__ Ws_g,
                       const float* __restrict__ Wd,   // either WdT [c][n] or Wd [n][c]
                       const int sc, const int sn,     // strides: idx = c*sc + n*sn
                       const float* __restrict__ Wb,
                       float* __restrict__ out) {
  __shared__ __align__(16) __bf16 Xs[CT][LDSS];
  __shared__ __align__(16) __bf16 Ws[NT][LDSS];

  const int tid   = threadIdx.x;
  const int n_blk = blockIdx.x;   // 0..3
  const int c_blk = blockIdx.y;   // 0..2
  const int b     = blockIdx.z;   // 0..511

  const int c0 = c_blk * CT;
  const int n0 = n_blk * NT;

  const int lane  = tid & 63;
  const int wv    = tid >> 6;          // 4 waves: 2x2 over (c,n) 64x64 quadrants
  const int cq    = (wv >> 1) * 64;
  const int nq    = (wv & 1) * 64;
  const int lrow  = lane & 15;
  const int lquad = lane >> 4;

  const f32x4 zero = {0.f, 0.f, 0.f, 0.f};
  f32x4 acc[4][4];
  #pragma unroll
  for (int mi = 0; mi < 4; ++mi)
    #pragma unroll
    for (int ni = 0; ni < 4; ++ni)
      acc[mi][ni] = zero;

  const float* xb  = x    + (size_t)b  * (C_ * HW_) + (size_t)c0 * HW_;
  const float* wsb = Ws_g + (size_t)n0 * HW_;

  for (int ch = 0; ch < 2; ++ch) {
    const int k0 = ch * KCH;
    __syncthreads();   // previous chunk's reads done before overwrite
    // cooperative staging: 128 rows x 96 cols for both tiles, fp32 -> bf16
    for (int e = tid; e < CT * KCH; e += 256) {
      int r   = e / KCH;
      int col = e - r * KCH;
      int k   = k0 + col;
      float vx = 0.f, vw = 0.f;
      if (k < HW_) {
        vx = xb [r * HW_ + k];
        vw = wsb[r * HW_ + k];
      }
      Xs[r][col] = f2bf(vx);
      Ws[r][col] = f2bf(vw);
    }
    __syncthreads();

    #pragma unroll
    for (int s = 0; s < 3; ++s) {
      const int kc = s * 32 + lquad * 8;
      bf16x8 afr[4], bfr[4];
      #pragma unroll
      for (int mi = 0; mi < 4; ++mi)
        afr[mi] = *(const bf16x8*)&Xs[cq + mi * 16 + lrow][kc];
      #pragma unroll
      for (int ni = 0; ni < 4; ++ni)
        bfr[ni] = *(const bf16x8*)&Ws[nq + ni * 16 + lrow][kc];
      #pragma unroll
      for (int mi = 0; mi < 4; ++mi)
        #pragma unroll
        for (int ni = 0; ni < 4; ++ni)
          acc[mi][ni] = __builtin_amdgcn_mfma_f32_16x16x32_bf16(
              afr[mi], bfr[ni], acc[mi][ni], 0, 0, 0);
    }
  }

  // Epilogue: out[b,n] += sum_c P[c,n] * W_d[n,c]
  // C-layout: col(n) = lane&15, row(c) = (lane>>4)*4 + reg
  #pragma unroll
  for (int ni = 0; ni < 4; ++ni) {
    const int n = n0 + nq + ni * 16 + lrow;
    float s = 0.f;
    #pragma unroll
    for (int mi = 0; mi < 4; ++mi) {
      const int cbase = c0 + cq + mi * 16 + lquad * 4;
      #pragma unroll
      for (int i = 0; i < 4; ++i) {
        const int c = cbase + i;
        s += acc[mi][ni][i] * Wd[c * sc + n * sn];
      }
    }
    // combine the 4 lane-quads (same n, disjoint c ranges)
    s += __shfl_xor(s, 16, 64);
    s += __shfl_xor(s, 32, 64);
    if (lane < 16) {
      if (c_blk == 0 && cq == 0) s += Wb[n];   // bias exactly once per (b,n)
      atomicAdd(&out[(size_t)b * N_ + n], s);
    }
  }
}

extern "C" void kernel_launch(void* const* d_in, const int* in_sizes, int n_in,
                              void* d_out, int out_size, void* d_ws, size_t ws_size,
                              hipStream_t stream) {
  const float* x   = (const float*)d_in[0];   // [512,384,13,13]
  const float* Wsp = (const float*)d_in[1];   // [512,13,13]
  const float* Wd  = (const float*)d_in[2];   // [512,384]
  const float* Wb  = (const float*)d_in[3];   // [1,512]
  float* out = (float*)d_out;                 // [512,512] fp32

  hipMemsetAsync(d_out, 0, (size_t)out_size * sizeof(float), stream);

  const bool use_t = ws_size >= (size_t)C_ * N_ * sizeof(float);
  const float* wd_ptr = Wd;
  int sc = 1, sn = C_;               // direct: Wd[n*384 + c]
  if (use_t) {
    float* wdT = (float*)d_ws;
    transpose_wd_kernel<<<(C_ * N_ + 255) / 256, 256, 0, stream>>>(Wd, wdT);
    wd_ptr = wdT;
    sc = N_; sn = 1;                 // WdT[c*512 + n]
  }

  dim3 grid(N_ / NT, C_ / CT, B_);   // (4, 3, 512) = 6144 blocks
  conv_encoder_main<<<grid, 256, 0, stream>>>(x, Wsp, wd_ptr, sc, sn, Wb, out);
}

// Round 2
// 313.535 us; speedup vs baseline: 2.3744x; 2.3744x over previous
//
#include <hip/hip_runtime.h>

// out[b,n] = sum_{c,hw} x[b,c,hw] * W_s[n,hw] * W_d[n,c] + W_b[n]
// B=512, C=384, N=512, HW=169 (13x13).
//
// Fast path (needs ~76.5 MB workspace):
//   prepass: x (fp32) -> xp bf16 [b][ch=2][c][kk=96] (k=ch*96+kk, zero past 169)
//            W_s      -> wsp bf16 [ch=2][n][kk=96]
//            W_d      -> WdT fp32 [c][n]
//   main: per block (b, c-tile 128, n-tile 128): stage both tile-chunks via
//         global_load_lds dwordx4 LINEAR COPY (LDS layout == global layout),
//         6 K-steps of 16x16x32 bf16 MFMA -> 128x128 acc, epilogue multiplies
//         by WdT and reduces over c (regs + shfl), atomicAdd into zeroed out.
// Fallback: R1 kernel (scalar staging) if ws_size too small.

#define B_   512
#define C_   384
#define N_   512
#define HW_  169
#define KCH  96        // K per chunk (3 MFMA k-steps), 2 chunks = 192 padded K
#define CT   128
#define NT   128

#define XP_ELEMS   ((size_t)B_ * 2 * C_ * KCH)     // 37,748,736
#define WSP_ELEMS  ((size_t)2 * N_ * KCH)          // 98,304
#define WDT_ELEMS  ((size_t)C_ * N_)               // 196,608

typedef __bf16 bf16x8 __attribute__((ext_vector_type(8)));
typedef float f32x4  __attribute__((ext_vector_type(4)));

__device__ __forceinline__ __bf16 f2bf(float f) {
  union { float f; unsigned u; } v; v.f = f;
  unsigned r = (v.u + 0x7FFFu + ((v.u >> 16) & 1u)) >> 16;   // RNE
  unsigned short s = (unsigned short)r;
  return __builtin_bit_cast(__bf16, s);
}

// ---------------- prepass kernels ----------------

__global__ __launch_bounds__(256)
void prep_x_kernel(const float* __restrict__ x, __bf16* __restrict__ xp) {
  int idx = blockIdx.x * 256 + threadIdx.x;      // exact: 147456 blocks
  int kk = idx % KCH;
  int t  = idx / KCH;          // [b][ch][c]
  int c  = t % C_;
  int t2 = t / C_;
  int ch = t2 & 1;
  int b  = t2 >> 1;
  int k  = ch * KCH + kk;
  float v = (k < HW_) ? x[((size_t)b * C_ + c) * HW_ + k] : 0.f;
  xp[idx] = f2bf(v);
}

__global__ __launch_bounds__(256)
void prep_ws_kernel(const float* __restrict__ Ws, __bf16* __restrict__ wsp) {
  int idx = blockIdx.x * 256 + threadIdx.x;      // exact: 384 blocks
  int kk = idx % KCH;
  int t  = idx / KCH;          // [ch][n]
  int n  = t % N_;
  int ch = t / N_;
  int k  = ch * KCH + kk;
  float v = (k < HW_) ? Ws[(size_t)n * HW_ + k] : 0.f;
  wsp[idx] = f2bf(v);
}

__global__ void transpose_wd_kernel(const float* __restrict__ Wd,
                                    float* __restrict__ WdT) {
  int idx = blockIdx.x * 256 + threadIdx.x;   // [c][n]
  if (idx < C_ * N_) {
    int c = idx >> 9;
    int n = idx & (N_ - 1);
    WdT[idx] = Wd[n * C_ + c];
  }
}

// ---------------- fast main kernel ----------------

__global__ __launch_bounds__(256)
void conv_main_fast(const __bf16* __restrict__ xp,
                    const __bf16* __restrict__ wsp,
                    const float* __restrict__ WdT,   // [c][n]
                    const float* __restrict__ Wb,
                    float* __restrict__ out) {
  // LDS tiles are EXACT linear images of the global chunk slabs (24576 B each)
  __shared__ __align__(16) __bf16 Xs[CT * KCH];
  __shared__ __align__(16) __bf16 Ws[NT * KCH];

  const int tid   = threadIdx.x;
  const int n_blk = blockIdx.x;   // 0..3
  const int c_blk = blockIdx.y;   // 0..2
  const int b     = blockIdx.z;   // 0..511

  const int c0 = c_blk * CT;
  const int n0 = n_blk * NT;

  const int lane  = tid & 63;
  const int wv    = tid >> 6;          // 4 waves: 2x2 (c,n) 64x64 quadrants
  const int cq    = (wv >> 1) * 64;
  const int nq    = (wv & 1) * 64;
  const int lrow  = lane & 15;
  const int lquad = lane >> 4;

  const f32x4 zero = {0.f, 0.f, 0.f, 0.f};
  f32x4 acc[4][4];
  #pragma unroll
  for (int mi = 0; mi < 4; ++mi)
    #pragma unroll
    for (int ni = 0; ni < 4; ++ni)
      acc[mi][ni] = zero;

  for (int ch = 0; ch < 2; ++ch) {
    const char* xsrc = (const char*)(xp + (((size_t)b * 2 + ch) * C_ + c0) * KCH);
    const char* wsrc = (const char*)(wsp + (((size_t)ch * N_) + n0) * KCH);
    char* xdst = (char*)Xs;
    char* wdst = (char*)Ws;

    __syncthreads();   // previous chunk's LDS reads complete before overwrite
    // 24576 B per tile = 24 wave-instructions of 1024 B; wave wv takes 6 each.
    #pragma unroll
    for (int i = 0; i < 6; ++i) {
      const int j = i * 4 + wv;
      __builtin_amdgcn_global_load_lds(
          (const __attribute__((address_space(1))) void*)(xsrc + j * 1024 + lane * 16),
          (__attribute__((address_space(3))) void*)(xdst + j * 1024),
          16, 0, 0);
      __builtin_amdgcn_global_load_lds(
          (const __attribute__((address_space(1))) void*)(wsrc + j * 1024 + lane * 16),
          (__attribute__((address_space(3))) void*)(wdst + j * 1024),
          16, 0, 0);
    }
    __syncthreads();   // drain vmcnt (DMA) before fragment reads

    #pragma unroll
    for (int s = 0; s < 3; ++s) {
      const int kc = s * 32 + lquad * 8;
      bf16x8 afr[4], bfr[4];
      #pragma unroll
      for (int mi = 0; mi < 4; ++mi)
        afr[mi] = *(const bf16x8*)&Xs[(cq + mi * 16 + lrow) * KCH + kc];
      #pragma unroll
      for (int ni = 0; ni < 4; ++ni)
        bfr[ni] = *(const bf16x8*)&Ws[(nq + ni * 16 + lrow) * KCH + kc];
      #pragma unroll
      for (int mi = 0; mi < 4; ++mi)
        #pragma unroll
        for (int ni = 0; ni < 4; ++ni)
          acc[mi][ni] = __builtin_amdgcn_mfma_f32_16x16x32_bf16(
              afr[mi], bfr[ni], acc[mi][ni], 0, 0, 0);
    }
  }

  // Epilogue: out[b,n] += sum_c P[c,n] * W_d[n,c]
  // C-layout: col(n) = lane&15, row(c) = (lane>>4)*4 + reg   [verified R1]
  #pragma unroll
  for (int ni = 0; ni < 4; ++ni) {
    const int n = n0 + nq + ni * 16 + lrow;
    float s = 0.f;
    #pragma unroll
    for (int mi = 0; mi < 4; ++mi) {
      const int cbase = c0 + cq + mi * 16 + lquad * 4;
      #pragma unroll
      for (int i = 0; i < 4; ++i)
        s += acc[mi][ni][i] * WdT[(size_t)(cbase + i) * N_ + n];
    }
    s += __shfl_xor(s, 16, 64);
    s += __shfl_xor(s, 32, 64);
    if (lane < 16) {
      if (c_blk == 0 && cq == 0) s += Wb[n];   // bias once per (b,n)
      atomicAdd(&out[(size_t)b * N_ + n], s);
    }
  }
}

// ---------------- fallback (R1) main kernel ----------------

#define LDSS 104

__global__ __launch_bounds__(256)
void conv_main_fallback(const float* __restrict__ x,
                        const float* __restrict__ Ws_g,
                        const float* __restrict__ Wd,
                        const int sc, const int sn,
                        const float* __restrict__ Wb,
                        float* __restrict__ out) {
  __shared__ __align__(16) __bf16 Xs[CT][LDSS];
  __shared__ __align__(16) __bf16 Ws[NT][LDSS];

  const int tid   = threadIdx.x;
  const int n_blk = blockIdx.x;
  const int c_blk = blockIdx.y;
  const int b     = blockIdx.z;
  const int c0 = c_blk * CT;
  const int n0 = n_blk * NT;
  const int lane  = tid & 63;
  const int wv    = tid >> 6;
  const int cq    = (wv >> 1) * 64;
  const int nq    = (wv & 1) * 64;
  const int lrow  = lane & 15;
  const int lquad = lane >> 4;

  const f32x4 zero = {0.f, 0.f, 0.f, 0.f};
  f32x4 acc[4][4];
  #pragma unroll
  for (int mi = 0; mi < 4; ++mi)
    #pragma unroll
    for (int ni = 0; ni < 4; ++ni)
      acc[mi][ni] = zero;

  const float* xb  = x    + (size_t)b  * (C_ * HW_) + (size_t)c0 * HW_;
  const float* wsb = Ws_g + (size_t)n0 * HW_;

  for (int ch = 0; ch < 2; ++ch) {
    const int k0 = ch * KCH;
    __syncthreads();
    for (int e = tid; e < CT * KCH; e += 256) {
      int r   = e / KCH;
      int col = e - r * KCH;
      int k   = k0 + col;
      float vx = 0.f, vw = 0.f;
      if (k < HW_) {
        vx = xb [r * HW_ + k];
        vw = wsb[r * HW_ + k];
      }
      Xs[r][col] = f2bf(vx);
      Ws[r][col] = f2bf(vw);
    }
    __syncthreads();

    #pragma unroll
    for (int s = 0; s < 3; ++s) {
      const int kc = s * 32 + lquad * 8;
      bf16x8 afr[4], bfr[4];
      #pragma unroll
      for (int mi = 0; mi < 4; ++mi)
        afr[mi] = *(const bf16x8*)&Xs[cq + mi * 16 + lrow][kc];
      #pragma unroll
      for (int ni = 0; ni < 4; ++ni)
        bfr[ni] = *(const bf16x8*)&Ws[nq + ni * 16 + lrow][kc];
      #pragma unroll
      for (int mi = 0; mi < 4; ++mi)
        #pragma unroll
        for (int ni = 0; ni < 4; ++ni)
          acc[mi][ni] = __builtin_amdgcn_mfma_f32_16x16x32_bf16(
              afr[mi], bfr[ni], acc[mi][ni], 0, 0, 0);
    }
  }

  #pragma unroll
  for (int ni = 0; ni < 4; ++ni) {
    const int n = n0 + nq + ni * 16 + lrow;
    float s = 0.f;
    #pragma unroll
    for (int mi = 0; mi < 4; ++mi) {
      const int cbase = c0 + cq + mi * 16 + lquad * 4;
      #pragma unroll
      for (int i = 0; i < 4; ++i)
        s += acc[mi][ni][i] * Wd[(cbase + i) * sc + n * sn];
    }
    s += __shfl_xor(s, 16, 64);
    s += __shfl_xor(s, 32, 64);
    if (lane < 16) {
      if (c_blk == 0 && cq == 0) s += Wb[n];
      atomicAdd(&out[(size_t)b * N_ + n], s);
    }
  }
}

extern "C" void kernel_launch(void* const* d_in, const int* in_sizes, int n_in,
                              void* d_out, int out_size, void* d_ws, size_t ws_size,
                              hipStream_t stream) {
  const float* x   = (const float*)d_in[0];   // [512,384,13,13]
  const float* Wsp = (const float*)d_in[1];   // [512,13,13]
  const float* Wd  = (const float*)d_in[2];   // [512,384]
  const float* Wb  = (const float*)d_in[3];   // [1,512]
  float* out = (float*)d_out;                 // [512,512] fp32

  hipMemsetAsync(d_out, 0, (size_t)out_size * sizeof(float), stream);

  const size_t need = (XP_ELEMS + WSP_ELEMS) * sizeof(__bf16)
                    + WDT_ELEMS * sizeof(float);

  if (ws_size >= need) {
    __bf16* xp  = (__bf16*)d_ws;
    __bf16* wsp = xp + XP_ELEMS;
    float*  wdT = (float*)(wsp + WSP_ELEMS);

    prep_x_kernel <<<(int)(XP_ELEMS / 256), 256, 0, stream>>>(x, xp);
    prep_ws_kernel<<<(int)(WSP_ELEMS / 256), 256, 0, stream>>>(Wsp, wsp);
    transpose_wd_kernel<<<(C_ * N_ + 255) / 256, 256, 0, stream>>>(Wd, wdT);

    dim3 grid(N_ / NT, C_ / CT, B_);   // (4, 3, 512)
    conv_main_fast<<<grid, 256, 0, stream>>>(xp, wsp, wdT, Wb, out);
  } else {
    const float* wd_ptr = Wd;
    int sc = 1, sn = C_;
    if (ws_size >= WDT_ELEMS * sizeof(float)) {
      float* wdT = (float*)d_ws;
      transpose_wd_kernel<<<(C_ * N_ + 255) / 256, 256, 0, stream>>>(Wd, wdT);
      wd_ptr = wdT;
      sc = N_; sn = 1;
    }
    dim3 grid(N_ / NT, C_ / CT, B_);
    conv_main_fallback<<<grid, 256, 0, stream>>>(x, Wsp, wd_ptr, sc, sn, Wb, out);
  }
}

// Round 3
// 304.910 us; speedup vs baseline: 2.4416x; 1.0283x over previous
//
#include <hip/hip_runtime.h>

// out[b,n] = sum_{c,hw} x[b,c,hw] * W_s[n,hw] * W_d[n,c] + W_b[n]
// B=512, C=384, N=512, HW=169 (13x13).
//
// Fast path (needs ~76.5 MB workspace):
//   prep_x:  x (fp32) -> xp bf16 [b][ch=2][c][kk=96]  (k=ch*96+kk, zero pad past 169)
//            8 elems/thread: coalesced dword loads, 16B bf16x8 stores.
//   prep_aux: W_s -> wsp bf16 [ch][n][96]; W_d -> WdT fp32 [c][n].
//   main: grid (4 n_blks, 512 b). Per block: loop c-tiles (3) x chunks (2),
//         stage 24KB X-tile + 24KB Ws-tile via global_load_lds dwordx4 linear
//         copy, 3 K-steps of 16x16x32 bf16 MFMA into 128x128 acc; per c-tile
//         epilogue folds acc*WdT into register s[4]; final cross-wave LDS
//         reduce + bias + plain coalesced store (no atomics, no memset).

#define B_   512
#define C_   384
#define N_   512
#define HW_  169
#define KCH  96
#define CT   128
#define NT   128

#define XP_ELEMS   ((size_t)B_ * 2 * C_ * KCH)     // 37,748,736
#define WSP_ELEMS  ((size_t)2 * N_ * KCH)          // 98,304
#define WDT_ELEMS  ((size_t)C_ * N_)               // 196,608

typedef __bf16 bf16x8 __attribute__((ext_vector_type(8)));
typedef float f32x4  __attribute__((ext_vector_type(4)));

__device__ __forceinline__ __bf16 f2bf(float f) {
  union { float f; unsigned u; } v; v.f = f;
  unsigned r = (v.u + 0x7FFFu + ((v.u >> 16) & 1u)) >> 16;   // RNE
  unsigned short s = (unsigned short)r;
  return __builtin_bit_cast(__bf16, s);
}

// ---------------- prepass kernels ----------------

// 8 elems/thread. grid: B*2*C*12/256 = 18432 blocks, exact.
__global__ __launch_bounds__(256)
void prep_x_kernel(const float* __restrict__ x, __bf16* __restrict__ xp) {
  int t = blockIdx.x * 256 + threadIdx.x;
  int kk8 = (t % 12) * 8;
  int t2  = t / 12;            // [b][ch][c]
  int c   = t2 % C_;
  int t3  = t2 / C_;
  int ch  = t3 & 1;
  int b   = t3 >> 1;
  const float* src = x + ((size_t)b * C_ + c) * HW_;
  int kbase = ch * KCH + kk8;
  bf16x8 v;
  #pragma unroll
  for (int j = 0; j < 8; ++j) {
    int k = kbase + j;
    float f = (k < HW_) ? src[k] : 0.f;
    v[j] = f2bf(f);
  }
  *(bf16x8*)(xp + (size_t)t * 8) = v;
}

// wsp: 12288 threads x 8 elems; WdT: 196608 threads x 1. 816 blocks exact.
__global__ __launch_bounds__(256)
void prep_aux_kernel(const float* __restrict__ Ws,
                     const float* __restrict__ Wd,
                     __bf16* __restrict__ wsp,
                     float* __restrict__ WdT) {
  int t = blockIdx.x * 256 + threadIdx.x;
  if (t < 12288) {
    int kk8 = (t % 12) * 8;
    int t2  = t / 12;          // [ch][n]
    int n   = t2 % N_;
    int ch  = t2 / N_;
    const float* src = Ws + (size_t)n * HW_;
    int kbase = ch * KCH + kk8;
    bf16x8 v;
    #pragma unroll
    for (int j = 0; j < 8; ++j) {
      int k = kbase + j;
      float f = (k < HW_) ? src[k] : 0.f;
      v[j] = f2bf(f);
    }
    *(bf16x8*)(wsp + (size_t)t * 8) = v;
  } else {
    int i = t - 12288;         // [c][n]
    if (i < C_ * N_) {
      int c = i >> 9;
      int n = i & (N_ - 1);
      WdT[i] = Wd[n * C_ + c];
    }
  }
}

// ---------------- fast main kernel ----------------

__global__ __launch_bounds__(256)
void conv_main_fast(const __bf16* __restrict__ xp,
                    const __bf16* __restrict__ wsp,
                    const float* __restrict__ WdT,   // [c][n]
                    const float* __restrict__ Wb,
                    float* __restrict__ out) {
  __shared__ __align__(16) __bf16 Xs[CT * KCH];   // 24 KB, linear image
  __shared__ __align__(16) __bf16 Ws[NT * KCH];   // 24 KB, linear image
  __shared__ float red[4][64];                     // 1 KB cross-wave reduce

  const int tid   = threadIdx.x;
  const int n_blk = blockIdx.x;   // 0..3
  const int b     = blockIdx.y;   // 0..511
  const int n0    = n_blk * NT;

  const int lane  = tid & 63;
  const int wv    = tid >> 6;          // 4 waves: 2x2 (c,n) 64x64 quadrants
  const int cq    = (wv >> 1) * 64;
  const int nq    = (wv & 1) * 64;
  const int lrow  = lane & 15;
  const int lquad = lane >> 4;

  float s[4] = {0.f, 0.f, 0.f, 0.f};   // per-lane partial out for 4 n values

  for (int cb = 0; cb < 3; ++cb) {
    const f32x4 zero = {0.f, 0.f, 0.f, 0.f};
    f32x4 acc[4][4];
    #pragma unroll
    for (int mi = 0; mi < 4; ++mi)
      #pragma unroll
      for (int ni = 0; ni < 4; ++ni)
        acc[mi][ni] = zero;

    for (int ch = 0; ch < 2; ++ch) {
      const char* xsrc = (const char*)(xp + (((size_t)b * 2 + ch) * C_ + cb * CT) * KCH);
      const char* wsrc = (const char*)(wsp + (((size_t)ch * N_) + n0) * KCH);
      char* xdst = (char*)Xs;
      char* wdst = (char*)Ws;

      __syncthreads();   // previous stage's LDS reads complete before overwrite
      #pragma unroll
      for (int i = 0; i < 6; ++i) {
        const int j = i * 4 + wv;
        __builtin_amdgcn_global_load_lds(
            (const __attribute__((address_space(1))) void*)(xsrc + j * 1024 + lane * 16),
            (__attribute__((address_space(3))) void*)(xdst + j * 1024),
            16, 0, 0);
        __builtin_amdgcn_global_load_lds(
            (const __attribute__((address_space(1))) void*)(wsrc + j * 1024 + lane * 16),
            (__attribute__((address_space(3))) void*)(wdst + j * 1024),
            16, 0, 0);
      }
      __syncthreads();   // DMA drained before fragment reads

      #pragma unroll
      for (int ks = 0; ks < 3; ++ks) {
        const int kc = ks * 32 + lquad * 8;
        bf16x8 afr[4], bfr[4];
        #pragma unroll
        for (int mi = 0; mi < 4; ++mi)
          afr[mi] = *(const bf16x8*)&Xs[(cq + mi * 16 + lrow) * KCH + kc];
        #pragma unroll
        for (int ni = 0; ni < 4; ++ni)
          bfr[ni] = *(const bf16x8*)&Ws[(nq + ni * 16 + lrow) * KCH + kc];
        #pragma unroll
        for (int mi = 0; mi < 4; ++mi)
          #pragma unroll
          for (int ni = 0; ni < 4; ++ni)
            acc[mi][ni] = __builtin_amdgcn_mfma_f32_16x16x32_bf16(
                afr[mi], bfr[ni], acc[mi][ni], 0, 0, 0);
      }
    }

    // fold this c-tile: s[ni] += sum_c P[c,n] * WdT[c,n]
    // C-layout: col(n) = lane&15, row(c) = (lane>>4)*4 + reg   [verified R1/R2]
    #pragma unroll
    for (int ni = 0; ni < 4; ++ni) {
      const int n = n0 + nq + ni * 16 + lrow;
      #pragma unroll
      for (int mi = 0; mi < 4; ++mi) {
        const int cbase = cb * CT + cq + mi * 16 + lquad * 4;
        #pragma unroll
        for (int i = 0; i < 4; ++i)
          s[ni] += acc[mi][ni][i] * WdT[(size_t)(cbase + i) * N_ + n];
      }
    }
  }

  // intra-wave: combine the 4 lane-quads (disjoint c subsets, same n)
  #pragma unroll
  for (int ni = 0; ni < 4; ++ni) {
    s[ni] += __shfl_xor(s[ni], 16, 64);
    s[ni] += __shfl_xor(s[ni], 32, 64);
  }
  if (lane < 16) {
    #pragma unroll
    for (int ni = 0; ni < 4; ++ni)
      red[wv][ni * 16 + lrow] = s[ni];
  }
  __syncthreads();

  // cross-wave: waves {0,2} share nq=0, {1,3} share nq=64 (disjoint c halves)
  if (tid < NT) {
    const int half = tid >> 6;         // 0: n 0..63, 1: n 64..127
    const int idx  = tid & 63;
    const int n    = n0 + tid;
    float v = red[half][idx] + red[half + 2][idx] + Wb[n];
    out[(size_t)b * N_ + n] = v;
  }
}

// ---------------- fallback main kernel (scalar staging, R1-style) ----------------

#define LDSS 104

__global__ __launch_bounds__(256)
void conv_main_fallback(const float* __restrict__ x,
                        const float* __restrict__ Ws_g,
                        const float* __restrict__ Wd,
                        const float* __restrict__ Wb,
                        float* __restrict__ out) {
  __shared__ __align__(16) __bf16 Xs[CT][LDSS];
  __shared__ __align__(16) __bf16 Ws[NT][LDSS];

  const int tid   = threadIdx.x;
  const int n_blk = blockIdx.x;
  const int c_blk = blockIdx.y;
  const int b     = blockIdx.z;
  const int c0 = c_blk * CT;
  const int n0 = n_blk * NT;
  const int lane  = tid & 63;
  const int wv    = tid >> 6;
  const int cq    = (wv >> 1) * 64;
  const int nq    = (wv & 1) * 64;
  const int lrow  = lane & 15;
  const int lquad = lane >> 4;

  const f32x4 zero = {0.f, 0.f, 0.f, 0.f};
  f32x4 acc[4][4];
  #pragma unroll
  for (int mi = 0; mi < 4; ++mi)
    #pragma unroll
    for (int ni = 0; ni < 4; ++ni)
      acc[mi][ni] = zero;

  const float* xb  = x    + (size_t)b  * (C_ * HW_) + (size_t)c0 * HW_;
  const float* wsb = Ws_g + (size_t)n0 * HW_;

  for (int ch = 0; ch < 2; ++ch) {
    const int k0 = ch * KCH;
    __syncthreads();
    for (int e = tid; e < CT * KCH; e += 256) {
      int r   = e / KCH;
      int col = e - r * KCH;
      int k   = k0 + col;
      float vx = 0.f, vw = 0.f;
      if (k < HW_) {
        vx = xb [r * HW_ + k];
        vw = wsb[r * HW_ + k];
      }
      Xs[r][col] = f2bf(vx);
      Ws[r][col] = f2bf(vw);
    }
    __syncthreads();

    #pragma unroll
    for (int ks = 0; ks < 3; ++ks) {
      const int kc = ks * 32 + lquad * 8;
      bf16x8 afr[4], bfr[4];
      #pragma unroll
      for (int mi = 0; mi < 4; ++mi)
        afr[mi] = *(const bf16x8*)&Xs[cq + mi * 16 + lrow][kc];
      #pragma unroll
      for (int ni = 0; ni < 4; ++ni)
        bfr[ni] = *(const bf16x8*)&Ws[nq + ni * 16 + lrow][kc];
      #pragma unroll
      for (int mi = 0; mi < 4; ++mi)
        #pragma unroll
        for (int ni = 0; ni < 4; ++ni)
          acc[mi][ni] = __builtin_amdgcn_mfma_f32_16x16x32_bf16(
              afr[mi], bfr[ni], acc[mi][ni], 0, 0, 0);
    }
  }

  #pragma unroll
  for (int ni = 0; ni < 4; ++ni) {
    const int n = n0 + nq + ni * 16 + lrow;
    float sv = 0.f;
    #pragma unroll
    for (int mi = 0; mi < 4; ++mi) {
      const int cbase = c0 + cq + mi * 16 + lquad * 4;
      #pragma unroll
      for (int i = 0; i < 4; ++i)
        sv += acc[mi][ni][i] * Wd[(size_t)n * C_ + (cbase + i)];
    }
    sv += __shfl_xor(sv, 16, 64);
    sv += __shfl_xor(sv, 32, 64);
    if (lane < 16) {
      if (c_blk == 0 && cq == 0) sv += Wb[n];
      atomicAdd(&out[(size_t)b * N_ + n], sv);
    }
  }
}

extern "C" void kernel_launch(void* const* d_in, const int* in_sizes, int n_in,
                              void* d_out, int out_size, void* d_ws, size_t ws_size,
                              hipStream_t stream) {
  const float* x   = (const float*)d_in[0];   // [512,384,13,13]
  const float* Wsp = (const float*)d_in[1];   // [512,13,13]
  const float* Wd  = (const float*)d_in[2];   // [512,384]
  const float* Wb  = (const float*)d_in[3];   // [1,512]
  float* out = (float*)d_out;                 // [512,512] fp32

  const size_t need = (XP_ELEMS + WSP_ELEMS) * sizeof(__bf16)
                    + WDT_ELEMS * sizeof(float);

  if (ws_size >= need) {
    __bf16* xp  = (__bf16*)d_ws;
    __bf16* wsp = xp + XP_ELEMS;
    float*  wdT = (float*)(wsp + WSP_ELEMS);

    prep_x_kernel  <<<(int)(XP_ELEMS / 8 / 256), 256, 0, stream>>>(x, xp);
    prep_aux_kernel<<<(12288 + C_ * N_ + 255) / 256, 256, 0, stream>>>(Wsp, Wd, wsp, wdT);

    dim3 grid(N_ / NT, B_);   // (4, 512) = 2048 blocks
    conv_main_fast<<<grid, 256, 0, stream>>>(xp, wsp, wdT, Wb, out);
  } else {
    hipMemsetAsync(d_out, 0, (size_t)out_size * sizeof(float), stream);
    dim3 grid(N_ / NT, C_ / CT, B_);
    conv_main_fallback<<<grid, 256, 0, stream>>>(x, Wsp, Wd, Wb, out);
  }
}